// Round 3
// baseline (488.599 us; speedup 1.0000x reference)
//
#include <hip/hip_runtime.h>
#include <hip/hip_bf16.h>

#define NTOK 8192
#define DDIM 1024
#define NEXP 8
#define FDIM 2048
#define NKROW (NTOK * 2)   // 16384 expert-rows (top-2)
#define MAXT 80            // max 256-row tiles: 16384/256 + 8 rounding

typedef __attribute__((ext_vector_type(8))) short bf16x8;
typedef __attribute__((ext_vector_type(4))) short bf16x4;
typedef __attribute__((ext_vector_type(4))) float f32x4;

__device__ __forceinline__ unsigned short f2bf(float f) {
  union { float f; unsigned u; } v; v.f = f;
  unsigned r = v.u + 0x7fffu + ((v.u >> 16) & 1u);   // RNE
  return (unsigned short)(r >> 16);
}

// async global->LDS, 16B per lane; LDS dest wave-uniform base (+lane*16 implicit)
__device__ __forceinline__ void gl16(const short* g, short* l) {
  __builtin_amdgcn_global_load_lds(
      (const __attribute__((address_space(1))) void*)g,
      (__attribute__((address_space(3))) void*)l, 16, 0, 0);
}

// ---------------- gate: fp64-accum logits, softmax top-2, renorm ----------------
__global__ void gate_kernel(const float* __restrict__ x, const float* __restrict__ gw,
                            int* __restrict__ tk_e, float* __restrict__ tk_w) {
  int wave = threadIdx.x >> 6, lane = threadIdx.x & 63;
  int n = blockIdx.x * 4 + wave;
  const float* xr = x + (size_t)n * DDIM;
  float xv[16];
#pragma unroll
  for (int i = 0; i < 16; i++) xv[i] = xr[lane + i * 64];
  float lg[NEXP];
#pragma unroll
  for (int e = 0; e < NEXP; e++) {
    const float* gr = gw + e * DDIM;
    double a = 0.0;
#pragma unroll
    for (int i = 0; i < 16; i++) a += (double)xv[i] * (double)gr[lane + i * 64];
#pragma unroll
    for (int s = 32; s > 0; s >>= 1) a += __shfl_xor(a, s, 64);
    lg[e] = (float)a;
  }
  if (lane == 0) {
    int i1 = 0; float b1 = lg[0];
#pragma unroll
    for (int e = 1; e < NEXP; e++) if (lg[e] > b1) { b1 = lg[e]; i1 = e; }
    int i2 = -1; float b2 = -3.4e38f;
#pragma unroll
    for (int e = 0; e < NEXP; e++) if (e != i1 && lg[e] > b2) { b2 = lg[e]; i2 = e; }
    float ex = __expf(b2 - b1);
    float inv = 1.0f / (1.0f + ex);
    tk_e[n * 2 + 0] = i1; tk_w[n * 2 + 0] = inv;
    tk_e[n * 2 + 1] = i2; tk_w[n * 2 + 1] = ex * inv;
  }
}

// ------------- deterministic counting-sort of (token,k) -> expert rows -------------
__global__ void build_index(const int* __restrict__ tk_e, int* __restrict__ tk_row,
                            int* __restrict__ offsets, int* __restrict__ tileE,
                            int* __restrict__ tileRow, int* __restrict__ nTiles) {
  __shared__ int cnt[256][NEXP];
  __shared__ int tot[NEXP];
  __shared__ int off_s[NEXP];
  int t = threadIdx.x;
  int c[NEXP];
#pragma unroll
  for (int e = 0; e < NEXP; e++) c[e] = 0;
  int base = t * 64;
  for (int i = 0; i < 64; i++) {
    int te = tk_e[base + i];
#pragma unroll
    for (int e = 0; e < NEXP; e++) c[e] += (te == e) ? 1 : 0;
  }
#pragma unroll
  for (int e = 0; e < NEXP; e++) cnt[t][e] = c[e];
  __syncthreads();
  if (t < NEXP) {
    int run = 0;
    for (int i = 0; i < 256; i++) { int v = cnt[i][t]; cnt[i][t] = run; run += v; }
    tot[t] = run;
  }
  __syncthreads();
  if (t == 0) {
    int o = 0, tc = 0;
    for (int e = 0; e < NEXP; e++) {
      off_s[e] = o; offsets[e] = o;
      int ce = tot[e];
      for (int i = 0; i < ce; i += 256) { tileE[tc] = e; tileRow[tc] = o + i; tc++; }
      o += ce;
    }
    offsets[NEXP] = o;
    nTiles[0] = tc;
    for (int q = tc; q < MAXT; q++) { tileE[q] = 0; tileRow[q] = 0; }
  }
  __syncthreads();
#pragma unroll
  for (int e = 0; e < NEXP; e++) c[e] = cnt[t][e] + off_s[e];
  for (int i = 0; i < 64; i++) {
    int te = tk_e[base + i];
    int r = 0;
#pragma unroll
    for (int e = 0; e < NEXP; e++) r += (te == e) ? c[e] : 0;
    tk_row[base + i] = r;
#pragma unroll
    for (int e = 0; e < NEXP; e++) c[e] += (te == e) ? 1 : 0;
  }
}

// ------------- gather token rows to bf16 xg; record per-row token/weight -------------
__global__ void build_rows(const float* __restrict__ x, const float* __restrict__ tk_w,
                           const int* __restrict__ tk_row,
                           int* __restrict__ row_token, float* __restrict__ row_w,
                           short* __restrict__ xg) {
  int idx = blockIdx.x;          // 0..NKROW-1 = n*2+k
  int n = idx >> 1;
  int row = tk_row[idx];
  if (threadIdx.x == 0) { row_token[row] = n; row_w[row] = tk_w[idx]; }
  const float4* xr = (const float4*)(x + (size_t)n * DDIM);
  float4 v = xr[threadIdx.x];
  bf16x4 o;
  o[0] = (short)f2bf(v.x); o[1] = (short)f2bf(v.y);
  o[2] = (short)f2bf(v.z); o[3] = (short)f2bf(v.w);
  *(bf16x4*)(xg + (size_t)row * DDIM + threadIdx.x * 4) = o;
}

// ------------- tiled transpose + fp32->bf16: in [R][C] -> out [C][R] per expert -------------
__global__ void transpose_cvt(const float* __restrict__ in, short* __restrict__ out,
                              int R, int C) {
  __shared__ float tile[64][65];
  int e = blockIdx.z;
  int cB = blockIdx.x * 64;
  int rB = blockIdx.y * 64;
  const float* src = in + (size_t)e * R * C;
  short* dst = out + (size_t)e * R * C;
  int t = threadIdx.x;
  int lr = t >> 4;
  int lc = (t & 15) * 4;
#pragma unroll
  for (int i = 0; i < 4; i++) {
    const float* p = src + (size_t)(rB + lr + i * 16) * C + cB + lc;
    float4 v = *(const float4*)p;
    tile[lr + i * 16][lc + 0] = v.x;
    tile[lr + i * 16][lc + 1] = v.y;
    tile[lr + i * 16][lc + 2] = v.z;
    tile[lr + i * 16][lc + 3] = v.w;
  }
  __syncthreads();
  int oc = t >> 2;
  int orr = (t & 3) * 16;
  bf16x8 o0, o1;
#pragma unroll
  for (int q = 0; q < 8; q++) {
    o0[q] = (short)f2bf(tile[orr + q][oc]);
    o1[q] = (short)f2bf(tile[orr + 8 + q][oc]);
  }
  short* op = dst + (size_t)(cB + oc) * R + rB + orr;
  *(bf16x8*)op = o0;
  *(bf16x8*)(op + 8) = o1;
}

// =====================================================================
// 256x256 phased GEMM core. K units of 32; 4 LDS unit-slots (quad buffer);
// 2 phases/unit (qm halves), 16 MFMA each; vmcnt(4) counted, setprio.
// LDS chunk swizzle: block b = row'*4+g stored at b ^ (row'&3) (involution),
// applied on the global SOURCE of global_load_lds and on ds_read addrs.
// =====================================================================

// ------------- GEMM1: xg[rows,1024] x {wg,wu} -> SwiGLU -> h[rows,2048] bf16 -------------
__global__ __launch_bounds__(512, 2) void gemm1(
    const short* __restrict__ xg, const short* __restrict__ wg, const short* __restrict__ wu,
    const int* __restrict__ tileE, const int* __restrict__ tileRow,
    const int* __restrict__ nTiles, const int* __restrict__ offsets,
    short* __restrict__ h) {
  if ((int)blockIdx.y >= nTiles[0]) return;
  int e = tileE[blockIdx.y];
  int rowBase = tileRow[blockIdx.y];
  int segEnd = offsets[e + 1];
  int fB = blockIdx.x * 128;    // 128 f's -> 256 cols (gate | up)

  __shared__ __align__(16) char smem[131072];
  short* lds = (short*)smem;

  int tid = threadIdx.x;
  int w = tid >> 6, lane = tid & 63;
  int wr = w >> 2, wc = w & 3;
  int r15 = lane & 15, gg = lane >> 4;
  int srow = lane >> 2, soct = (lane & 3) ^ ((lane >> 2) & 3);
  int blk = r15 * 4 + (gg ^ (r15 & 3));     // swizzled 16B-block within 1KB chunk

  // staging sources (per-lane): A chunks 2w,2w+1 = rows rowBase+w*32 .. +31
  const short* aS0 = xg + (size_t)(rowBase + w * 32 + srow) * DDIM + soct * 8;
  const short* aS1 = aS0 + 16 * DDIM;
  // B chunks 2w,2w+1: cols-in-tile 32w..32w+31; <128 gate, >=128 up (same f range)
  const short* bmat = (w < 4) ? wg : wu;
  const short* bS0 = bmat + ((size_t)e * FDIM + fB + ((2 * w) & 7) * 16 + srow) * DDIM + soct * 8;
  const short* bS1 = bS0 + 16 * DDIM;

  int fragA = wr * 8 * 512 + blk * 8;            // + m*512 + slot*16384
  int fragB = 8192 + wc * 4 * 512 + blk * 8;     // + n*512 + slot*16384
  int dstA = w * 1024;                            // chunks 2w,2w+1 (shorts)
  int dstB = 8192 + w * 1024;

  f32x4 acc[8][4];
#pragma unroll
  for (int m = 0; m < 8; m++)
#pragma unroll
    for (int n = 0; n < 4; n++) acc[m][n] = (f32x4){0.f, 0.f, 0.f, 0.f};

#define STAGE_A1(u_) { int s_ = ((u_) & 3) * 16384; int k_ = (u_) * 32; \
    gl16(aS0 + k_, lds + s_ + dstA); gl16(aS1 + k_, lds + s_ + dstA + 512); }
#define STAGE_B1(u_) { int s_ = ((u_) & 3) * 16384; int k_ = (u_) * 32; \
    gl16(bS0 + k_, lds + s_ + dstB); gl16(bS1 + k_, lds + s_ + dstB + 512); }

  STAGE_A1(0); STAGE_B1(0); STAGE_A1(1); STAGE_B1(1);
  asm volatile("s_waitcnt vmcnt(4)" ::: "memory");
  __builtin_amdgcn_s_barrier();

  for (int u = 0; u < 32; ++u) {
    int s = (u & 3) * 16384;
    bf16x8 a0[4], b0[4];
#pragma unroll
    for (int m = 0; m < 4; m++) a0[m] = *(const bf16x8*)(lds + s + fragA + m * 512);
#pragma unroll
    for (int n = 0; n < 4; n++) b0[n] = *(const bf16x8*)(lds + s + fragB + n * 512);
    if (u + 2 < 32) STAGE_A1(u + 2);
    __builtin_amdgcn_s_barrier();
    __builtin_amdgcn_s_setprio(1);
#pragma unroll
    for (int m = 0; m < 4; m++)
#pragma unroll
      for (int n = 0; n < 4; n++)
        acc[m][n] = __builtin_amdgcn_mfma_f32_16x16x32_bf16(a0[m], b0[n], acc[m][n], 0, 0, 0);
    __builtin_amdgcn_s_setprio(0);
    bf16x8 a1[4];
#pragma unroll
    for (int m = 0; m < 4; m++) a1[m] = *(const bf16x8*)(lds + s + fragA + (4 + m) * 512);
    if (u + 2 < 32) { STAGE_B1(u + 2); asm volatile("s_waitcnt vmcnt(4)" ::: "memory"); }
    else            { asm volatile("s_waitcnt vmcnt(0)" ::: "memory"); }
    __builtin_amdgcn_s_barrier();
    __builtin_amdgcn_s_setprio(1);
#pragma unroll
    for (int m = 0; m < 4; m++)
#pragma unroll
      for (int n = 0; n < 4; n++)
        acc[4 + m][n] = __builtin_amdgcn_mfma_f32_16x16x32_bf16(a1[m], b0[n], acc[4 + m][n], 0, 0, 0);
    __builtin_amdgcn_s_setprio(0);
  }

  // ---- SwiGLU epilogue: up waves (wc>=2) publish f32; gate waves fuse; coalesced store
  __syncthreads();
  float* uf = (float*)smem;   // [256][128] f32 (row-in-tile, f-in-block)
  if (wc >= 2) {
#pragma unroll
    for (int m = 0; m < 8; m++)
#pragma unroll
      for (int n = 0; n < 4; n++)
#pragma unroll
        for (int j = 0; j < 4; j++)
          uf[(wr * 128 + m * 16 + gg * 4 + j) * 128 + (wc - 2) * 64 + n * 16 + r15] = acc[m][n][j];
  }
  __syncthreads();
  if (wc < 2) {
#pragma unroll
    for (int m = 0; m < 8; m++)
#pragma unroll
      for (int n = 0; n < 4; n++)
#pragma unroll
        for (int j = 0; j < 4; j++) {
          int row = wr * 128 + m * 16 + gg * 4 + j;
          int col = wc * 64 + n * 16 + r15;
          float g = acc[m][n][j];
          float uv = uf[row * 128 + col];
          uf[row * 128 + col] = g / (1.0f + __expf(-g)) * uv;
        }
  }
  __syncthreads();
  int r_t = tid >> 1, part = tid & 1;
  int grow = rowBase + r_t;
  if (grow < segEnd) {
    short* hp = h + (size_t)grow * FDIM + fB + part * 64;
    const float* src = uf + r_t * 128 + part * 64;
#pragma unroll
    for (int i = 0; i < 8; i++) {
      bf16x8 o;
#pragma unroll
      for (int q = 0; q < 8; q++) o[q] = (short)f2bf(src[i * 8 + q]);
      *(bf16x8*)(hp + i * 8) = o;
    }
  }
#undef STAGE_A1
#undef STAGE_B1
}

// ------------- GEMM2: h[rows,2048] x wb2[d,f] -> y[token] += w * out (split-K=2) -------------
__global__ __launch_bounds__(512, 2) void gemm2(
    const short* __restrict__ h, const short* __restrict__ w2,
    const int* __restrict__ tileE, const int* __restrict__ tileRow,
    const int* __restrict__ nTiles, const int* __restrict__ offsets,
    const int* __restrict__ row_token, const float* __restrict__ row_w,
    float* __restrict__ y) {
  if ((int)blockIdx.y >= nTiles[0]) return;
  int e = tileE[blockIdx.y];
  int rowBase = tileRow[blockIdx.y];
  int segEnd = offsets[e + 1];
  int dB = blockIdx.x * 256;
  int koff = blockIdx.z * 1024;

  __shared__ __align__(16) char smem[131072];
  short* lds = (short*)smem;

  int tid = threadIdx.x;
  int w = tid >> 6, lane = tid & 63;
  int wr = w >> 2, wc = w & 3;
  int r15 = lane & 15, gg = lane >> 4;
  int srow = lane >> 2, soct = (lane & 3) ^ ((lane >> 2) & 3);
  int blk = r15 * 4 + (gg ^ (r15 & 3));

  const short* aS0 = h + (size_t)(rowBase + w * 32 + srow) * FDIM + koff + soct * 8;
  const short* aS1 = aS0 + 16 * FDIM;
  const short* bS0 = w2 + ((size_t)e * DDIM + dB + w * 32 + srow) * FDIM + koff + soct * 8;
  const short* bS1 = bS0 + 16 * FDIM;

  int fragA = wr * 8 * 512 + blk * 8;
  int fragB = 8192 + wc * 4 * 512 + blk * 8;
  int dstA = w * 1024;
  int dstB = 8192 + w * 1024;

  f32x4 acc[8][4];
#pragma unroll
  for (int m = 0; m < 8; m++)
#pragma unroll
    for (int n = 0; n < 4; n++) acc[m][n] = (f32x4){0.f, 0.f, 0.f, 0.f};

#define STAGE_A2(u_) { int s_ = ((u_) & 3) * 16384; int k_ = (u_) * 32; \
    gl16(aS0 + k_, lds + s_ + dstA); gl16(aS1 + k_, lds + s_ + dstA + 512); }
#define STAGE_B2(u_) { int s_ = ((u_) & 3) * 16384; int k_ = (u_) * 32; \
    gl16(bS0 + k_, lds + s_ + dstB); gl16(bS1 + k_, lds + s_ + dstB + 512); }

  STAGE_A2(0); STAGE_B2(0); STAGE_A2(1); STAGE_B2(1);
  asm volatile("s_waitcnt vmcnt(4)" ::: "memory");
  __builtin_amdgcn_s_barrier();

  for (int u = 0; u < 32; ++u) {
    int s = (u & 3) * 16384;
    bf16x8 a0[4], b0[4];
#pragma unroll
    for (int m = 0; m < 4; m++) a0[m] = *(const bf16x8*)(lds + s + fragA + m * 512);
#pragma unroll
    for (int n = 0; n < 4; n++) b0[n] = *(const bf16x8*)(lds + s + fragB + n * 512);
    if (u + 2 < 32) STAGE_A2(u + 2);
    __builtin_amdgcn_s_barrier();
    __builtin_amdgcn_s_setprio(1);
#pragma unroll
    for (int m = 0; m < 4; m++)
#pragma unroll
      for (int n = 0; n < 4; n++)
        acc[m][n] = __builtin_amdgcn_mfma_f32_16x16x32_bf16(a0[m], b0[n], acc[m][n], 0, 0, 0);
    __builtin_amdgcn_s_setprio(0);
    bf16x8 a1[4];
#pragma unroll
    for (int m = 0; m < 4; m++) a1[m] = *(const bf16x8*)(lds + s + fragA + (4 + m) * 512);
    if (u + 2 < 32) { STAGE_B2(u + 2); asm volatile("s_waitcnt vmcnt(4)" ::: "memory"); }
    else            { asm volatile("s_waitcnt vmcnt(0)" ::: "memory"); }
    __builtin_amdgcn_s_barrier();
    __builtin_amdgcn_s_setprio(1);
#pragma unroll
    for (int m = 0; m < 4; m++)
#pragma unroll
      for (int n = 0; n < 4; n++)
        acc[4 + m][n] = __builtin_amdgcn_mfma_f32_16x16x32_bf16(a1[m], b0[n], acc[4 + m][n], 0, 0, 0);
    __builtin_amdgcn_s_setprio(0);
  }

#pragma unroll
  for (int m = 0; m < 8; m++) {
#pragma unroll
    for (int j = 0; j < 4; j++) {
      int grow = rowBase + wr * 128 + m * 16 + gg * 4 + j;
      if (grow < segEnd) {
        int tok = row_token[grow];
        float wgt = row_w[grow];
        float* yr = y + (size_t)tok * DDIM + dB + wc * 64 + r15;
#pragma unroll
        for (int n = 0; n < 4; n++)
          atomicAdd(yr + n * 16, wgt * acc[m][n][j]);
      }
    }
  }
#undef STAGE_A2
#undef STAGE_B2
}

extern "C" void kernel_launch(void* const* d_in, const int* in_sizes, int n_in,
                              void* d_out, int out_size, void* d_ws, size_t ws_size,
                              hipStream_t stream) {
  const float* x      = (const float*)d_in[0];
  const float* gw     = (const float*)d_in[1];
  const float* w_gate = (const float*)d_in[2];
  const float* w_up   = (const float*)d_in[3];
  const float* w_down = (const float*)d_in[4];
  float* y = (float*)d_out;
  (void)in_sizes; (void)n_in; (void)ws_size;

  char* ws = (char*)d_ws;
  size_t off = 0;
  auto alloc = [&](size_t bytes) -> void* {
    void* p = ws + off; off += (bytes + 255) & ~(size_t)255; return p;
  };
  short* wb1g      = (short*)alloc((size_t)NEXP * FDIM * DDIM * 2);   // [E][F][D] bf16
  short* wb1u      = (short*)alloc((size_t)NEXP * FDIM * DDIM * 2);   // [E][F][D] bf16
  short* wb2       = (short*)alloc((size_t)NEXP * DDIM * FDIM * 2);   // [E][D][F] bf16
  short* xg        = (short*)alloc((size_t)(NKROW + 256) * DDIM * 2); // gathered rows (+tile pad)
  short* hbuf      = (short*)alloc((size_t)(NKROW + 256) * FDIM * 2); // SwiGLU output (+tile pad)
  int*   tk_e      = (int*)alloc((size_t)NKROW * 4);
  float* tk_w      = (float*)alloc((size_t)NKROW * 4);
  int*   tk_row    = (int*)alloc((size_t)NKROW * 4);
  int*   row_token = (int*)alloc((size_t)(NKROW + 256) * 4);
  float* row_w     = (float*)alloc((size_t)(NKROW + 256) * 4);
  int*   tileE     = (int*)alloc(MAXT * 4);
  int*   tileRow   = (int*)alloc(MAXT * 4);
  int*   nTiles    = (int*)alloc(256);
  int*   offsets   = (int*)alloc(256);

  hipMemsetAsync(d_out, 0, (size_t)out_size * 4, stream);

  transpose_cvt<<<dim3(FDIM / 64, DDIM / 64, NEXP), 256, 0, stream>>>(w_gate, wb1g, DDIM, FDIM);
  transpose_cvt<<<dim3(FDIM / 64, DDIM / 64, NEXP), 256, 0, stream>>>(w_up,   wb1u, DDIM, FDIM);
  transpose_cvt<<<dim3(DDIM / 64, FDIM / 64, NEXP), 256, 0, stream>>>(w_down, wb2,  FDIM, DDIM);
  gate_kernel<<<NTOK / 4, 256, 0, stream>>>(x, gw, tk_e, tk_w);
  build_index<<<1, 256, 0, stream>>>(tk_e, tk_row, offsets, tileE, tileRow, nTiles);
  build_rows<<<NKROW, 256, 0, stream>>>(x, tk_w, tk_row, row_token, row_w, xg);
  gemm1<<<dim3(FDIM / 128, MAXT), 512, 0, stream>>>(xg, wb1g, wb1u, tileE, tileRow, nTiles, offsets, hbuf);
  gemm2<<<dim3(DDIM / 256, MAXT, 2), 512, 0, stream>>>(hbuf, wb2, tileE, tileRow, nTiles, offsets, row_token, row_w, y);
}

// Round 4
// 389.409 us; speedup vs baseline: 1.2547x; 1.2547x over previous
//
#include <hip/hip_runtime.h>
#include <hip/hip_bf16.h>

#define NTOK 8192
#define DDIM 1024
#define NEXP 8
#define FDIM 2048
#define NKROW (NTOK * 2)   // 16384 expert-rows (top-2)
#define MAXT 80            // max 256-row tiles: 16384/256 + 8 rounding

typedef __attribute__((ext_vector_type(8))) short bf16x8;
typedef __attribute__((ext_vector_type(4))) short bf16x4;
typedef __attribute__((ext_vector_type(4))) float f32x4;

__device__ __forceinline__ unsigned short f2bf(float f) {
  union { float f; unsigned u; } v; v.f = f;
  unsigned r = v.u + 0x7fffu + ((v.u >> 16) & 1u);   // RNE
  return (unsigned short)(r >> 16);
}
__device__ __forceinline__ float bf2f(short s) {
  union { unsigned u; float f; } v; v.u = ((unsigned)(unsigned short)s) << 16; return v.f;
}

// async global->LDS, 16B per lane; LDS dest wave-uniform base (+lane*16 implicit)
__device__ __forceinline__ void gl16(const short* g, short* l) {
  __builtin_amdgcn_global_load_lds(
      (const __attribute__((address_space(1))) void*)g,
      (__attribute__((address_space(3))) void*)l, 16, 0, 0);
}

// ---------------- gate: fp64-accum logits, softmax top-2, renorm ----------------
__global__ void gate_kernel(const float* __restrict__ x, const float* __restrict__ gw,
                            int* __restrict__ tk_e, float* __restrict__ tk_w) {
  int wave = threadIdx.x >> 6, lane = threadIdx.x & 63;
  int n = blockIdx.x * 4 + wave;
  const float* xr = x + (size_t)n * DDIM;
  float xv[16];
#pragma unroll
  for (int i = 0; i < 16; i++) xv[i] = xr[lane + i * 64];
  float lg[NEXP];
#pragma unroll
  for (int e = 0; e < NEXP; e++) {
    const float* gr = gw + e * DDIM;
    double a = 0.0;
#pragma unroll
    for (int i = 0; i < 16; i++) a += (double)xv[i] * (double)gr[lane + i * 64];
#pragma unroll
    for (int s = 32; s > 0; s >>= 1) a += __shfl_xor(a, s, 64);
    lg[e] = (float)a;
  }
  if (lane == 0) {
    int i1 = 0; float b1 = lg[0];
#pragma unroll
    for (int e = 1; e < NEXP; e++) if (lg[e] > b1) { b1 = lg[e]; i1 = e; }
    int i2 = -1; float b2 = -3.4e38f;
#pragma unroll
    for (int e = 0; e < NEXP; e++) if (e != i1 && lg[e] > b2) { b2 = lg[e]; i2 = e; }
    float ex = __expf(b2 - b1);
    float inv = 1.0f / (1.0f + ex);
    tk_e[n * 2 + 0] = i1; tk_w[n * 2 + 0] = inv;
    tk_e[n * 2 + 1] = i2; tk_w[n * 2 + 1] = ex * inv;
  }
}

// ------------- deterministic counting-sort of (token,k) -> expert rows -------------
__global__ void build_index(const int* __restrict__ tk_e, int* __restrict__ tk_row,
                            int* __restrict__ offsets, int* __restrict__ tileE,
                            int* __restrict__ tileRow, int* __restrict__ nTiles) {
  __shared__ int cnt[256][NEXP];
  __shared__ int tot[NEXP];
  __shared__ int off_s[NEXP];
  int t = threadIdx.x;
  int c[NEXP];
#pragma unroll
  for (int e = 0; e < NEXP; e++) c[e] = 0;
  int base = t * 64;
  for (int i = 0; i < 64; i++) {
    int te = tk_e[base + i];
#pragma unroll
    for (int e = 0; e < NEXP; e++) c[e] += (te == e) ? 1 : 0;
  }
#pragma unroll
  for (int e = 0; e < NEXP; e++) cnt[t][e] = c[e];
  __syncthreads();
  if (t < NEXP) {
    int run = 0;
    for (int i = 0; i < 256; i++) { int v = cnt[i][t]; cnt[i][t] = run; run += v; }
    tot[t] = run;
  }
  __syncthreads();
  if (t == 0) {
    int o = 0, tc = 0;
    for (int e = 0; e < NEXP; e++) {
      off_s[e] = o; offsets[e] = o;
      int ce = tot[e];
      for (int i = 0; i < ce; i += 256) { tileE[tc] = e; tileRow[tc] = o + i; tc++; }
      o += ce;
    }
    offsets[NEXP] = o;
    nTiles[0] = tc;
    for (int q = tc; q < MAXT; q++) { tileE[q] = 0; tileRow[q] = 0; }
  }
  __syncthreads();
#pragma unroll
  for (int e = 0; e < NEXP; e++) c[e] = cnt[t][e] + off_s[e];
  for (int i = 0; i < 64; i++) {
    int te = tk_e[base + i];
    int r = 0;
#pragma unroll
    for (int e = 0; e < NEXP; e++) r += (te == e) ? c[e] : 0;
    tk_row[base + i] = r;
#pragma unroll
    for (int e = 0; e < NEXP; e++) c[e] += (te == e) ? 1 : 0;
  }
}

// ------------- gather token rows to bf16 xg -------------
__global__ void build_rows(const float* __restrict__ x,
                           const int* __restrict__ tk_row,
                           short* __restrict__ xg) {
  int idx = blockIdx.x;          // 0..NKROW-1 = n*2+k
  int n = idx >> 1;
  int row = tk_row[idx];
  const float4* xr = (const float4*)(x + (size_t)n * DDIM);
  float4 v = xr[threadIdx.x];
  bf16x4 o;
  o[0] = (short)f2bf(v.x); o[1] = (short)f2bf(v.y);
  o[2] = (short)f2bf(v.z); o[3] = (short)f2bf(v.w);
  *(bf16x4*)(xg + (size_t)row * DDIM + threadIdx.x * 4) = o;
}

// ------------- tiled transpose + fp32->bf16: in [R][C] -> out [C][R] per expert -------------
__global__ void transpose_cvt(const float* __restrict__ in, short* __restrict__ out,
                              int R, int C) {
  __shared__ float tile[64][65];
  int e = blockIdx.z;
  int cB = blockIdx.x * 64;
  int rB = blockIdx.y * 64;
  const float* src = in + (size_t)e * R * C;
  short* dst = out + (size_t)e * R * C;
  int t = threadIdx.x;
  int lr = t >> 4;
  int lc = (t & 15) * 4;
#pragma unroll
  for (int i = 0; i < 4; i++) {
    const float* p = src + (size_t)(rB + lr + i * 16) * C + cB + lc;
    float4 v = *(const float4*)p;
    tile[lr + i * 16][lc + 0] = v.x;
    tile[lr + i * 16][lc + 1] = v.y;
    tile[lr + i * 16][lc + 2] = v.z;
    tile[lr + i * 16][lc + 3] = v.w;
  }
  __syncthreads();
  int oc = t >> 2;
  int orr = (t & 3) * 16;
  bf16x8 o0, o1;
#pragma unroll
  for (int q = 0; q < 8; q++) {
    o0[q] = (short)f2bf(tile[orr + q][oc]);
    o1[q] = (short)f2bf(tile[orr + 8 + q][oc]);
  }
  short* op = dst + (size_t)(cB + oc) * R + rB + orr;
  *(bf16x8*)op = o0;
  *(bf16x8*)(op + 8) = o1;
}

// =====================================================================
// 256x256 phased GEMM core. K units of 32; 4 LDS unit-slots (quad buffer);
// 2 phases/unit, 16 MFMA each; counted vmcnt(4); setprio around MFMA.
// Conflict-free LDS swizzle: within each 1KB chunk (16 rows x 4 16B-slots),
// block (r,q) holds K-octet q ^ ((r>>1)&3).  Slot group = 4*(r&1) + q'
// has period 8 in r -> 2 lanes/bank-group = free (m136).
// Applied on the global SOURCE (gl16 linear dest, rule #21) and on ds_read.
// =====================================================================

// ------------- GEMM1: xg[rows,1024] x {wg,wu} -> SwiGLU in-reg -> h[rows,2048] bf16 -------------
__global__ __launch_bounds__(512, 2) void gemm1(
    const short* __restrict__ xg, const short* __restrict__ wg, const short* __restrict__ wu,
    const int* __restrict__ tileE, const int* __restrict__ tileRow,
    const int* __restrict__ nTiles, const int* __restrict__ offsets,
    short* __restrict__ h) {
  if ((int)blockIdx.y >= nTiles[0]) return;
  int e = tileE[blockIdx.y];
  int rowBase = tileRow[blockIdx.y];
  int segEnd = offsets[e + 1];
  int fB = blockIdx.x * 128;    // 128 f's -> 256 tile cols: [quad][g16|g16|u16|u16]

  __shared__ __align__(16) char smem[131072];
  short* lds = (short*)smem;

  int tid = threadIdx.x;
  int w = tid >> 6, lane = tid & 63;
  int wr = w >> 2, wc = w & 3;
  int r15 = lane & 15, gg = lane >> 4;
  int srow = lane >> 2;
  int soct = (lane & 3) ^ ((lane >> 3) & 3);          // swizzled source K-octet
  int blk = r15 * 4 + (gg ^ ((r15 >> 1) & 3));        // swizzled 16B-block on read

  // A: wave w stages rows [w*32, w*32+32)
  const short* aS0 = xg + (size_t)(rowBase + w * 32 + srow) * DDIM + soct * 8;
  const short* aS1 = aS0 + 16 * DDIM;
  // B: tile col c: quad=c>>6, half=(c>>5)&1 (0=gate,1=up), f = fB + quad*32 + (c&31)
  // wave w stages cols [w*32, w*32+32)
  const short* bmat = (w & 1) ? wu : wg;
  const short* bS0 = bmat + ((size_t)e * FDIM + fB + (w >> 1) * 32 + srow) * DDIM + soct * 8;
  const short* bS1 = bS0 + 16 * DDIM;

  int fragA = wr * 8 * 512 + blk * 8;            // + m*512 + slot*16384 (shorts)
  int fragB = 8192 + wc * 4 * 512 + blk * 8;     // + n*512 + slot*16384
  int dstA = w * 1024;
  int dstB = 8192 + w * 1024;

  f32x4 acc[8][4];
#pragma unroll
  for (int m = 0; m < 8; m++)
#pragma unroll
    for (int n = 0; n < 4; n++) acc[m][n] = (f32x4){0.f, 0.f, 0.f, 0.f};

#define STAGE_A1(u_) { int s_ = ((u_) & 3) * 16384; int k_ = (u_) * 32; \
    gl16(aS0 + k_, lds + s_ + dstA); gl16(aS1 + k_, lds + s_ + dstA + 512); }
#define STAGE_B1(u_) { int s_ = ((u_) & 3) * 16384; int k_ = (u_) * 32; \
    gl16(bS0 + k_, lds + s_ + dstB); gl16(bS1 + k_, lds + s_ + dstB + 512); }

  STAGE_A1(0); STAGE_B1(0); STAGE_A1(1); STAGE_B1(1);
  asm volatile("s_waitcnt vmcnt(4)" ::: "memory");
  __builtin_amdgcn_s_barrier();

  for (int u = 0; u < 32; ++u) {
    int s = (u & 3) * 16384;
    bf16x8 a0[4], b0[4];
#pragma unroll
    for (int m = 0; m < 4; m++) a0[m] = *(const bf16x8*)(lds + s + fragA + m * 512);
#pragma unroll
    for (int n = 0; n < 4; n++) b0[n] = *(const bf16x8*)(lds + s + fragB + n * 512);
    if (u + 2 < 32) STAGE_A1(u + 2);
    __builtin_amdgcn_s_barrier();
    __builtin_amdgcn_s_setprio(1);
#pragma unroll
    for (int m = 0; m < 4; m++)
#pragma unroll
      for (int n = 0; n < 4; n++)
        acc[m][n] = __builtin_amdgcn_mfma_f32_16x16x32_bf16(a0[m], b0[n], acc[m][n], 0, 0, 0);
    __builtin_amdgcn_s_setprio(0);
    bf16x8 a1[4];
#pragma unroll
    for (int m = 0; m < 4; m++) a1[m] = *(const bf16x8*)(lds + s + fragA + (4 + m) * 512);
    if (u + 2 < 32) { STAGE_B1(u + 2); asm volatile("s_waitcnt vmcnt(4)" ::: "memory"); }
    else            { asm volatile("s_waitcnt vmcnt(0)" ::: "memory"); }
    __builtin_amdgcn_s_barrier();
    __builtin_amdgcn_s_setprio(1);
#pragma unroll
    for (int m = 0; m < 4; m++)
#pragma unroll
      for (int n = 0; n < 4; n++)
        acc[4 + m][n] = __builtin_amdgcn_mfma_f32_16x16x32_bf16(a1[m], b0[n], acc[4 + m][n], 0, 0, 0);
    __builtin_amdgcn_s_setprio(0);
  }

  // ---- SwiGLU fully in-register: acc[m][0..1]=gate, acc[m][2..3]=up (same f cols)
#pragma unroll
  for (int m = 0; m < 8; m++) {
#pragma unroll
    for (int j = 0; j < 4; j++) {
      int grow = rowBase + wr * 128 + m * 16 + gg * 4 + j;
      if (grow < segEnd) {
        short* hp = h + (size_t)grow * FDIM + fB + wc * 32 + r15;
#pragma unroll
        for (int n = 0; n < 2; n++) {
          float g = acc[m][n][j];
          float uv = acc[m][n + 2][j];
          float hv = g / (1.0f + __expf(-g)) * uv;
          hp[n * 16] = (short)f2bf(hv);
        }
      }
    }
  }
#undef STAGE_A1
#undef STAGE_B1
}

// ------------- GEMM2: h[rows,2048] x wb2[d,f] -> outs[row,1024] bf16 (no atomics) -------------
__global__ __launch_bounds__(512, 2) void gemm2(
    const short* __restrict__ h, const short* __restrict__ w2,
    const int* __restrict__ tileE, const int* __restrict__ tileRow,
    const int* __restrict__ nTiles, const int* __restrict__ offsets,
    short* __restrict__ outs) {
  if ((int)blockIdx.y >= nTiles[0]) return;
  int e = tileE[blockIdx.y];
  int rowBase = tileRow[blockIdx.y];
  int segEnd = offsets[e + 1];
  int dB = blockIdx.x * 256;

  __shared__ __align__(16) char smem[131072];
  short* lds = (short*)smem;

  int tid = threadIdx.x;
  int w = tid >> 6, lane = tid & 63;
  int wr = w >> 2, wc = w & 3;
  int r15 = lane & 15, gg = lane >> 4;
  int srow = lane >> 2;
  int soct = (lane & 3) ^ ((lane >> 3) & 3);
  int blk = r15 * 4 + (gg ^ ((r15 >> 1) & 3));

  const short* aS0 = h + (size_t)(rowBase + w * 32 + srow) * FDIM + soct * 8;
  const short* aS1 = aS0 + 16 * FDIM;
  const short* bS0 = w2 + ((size_t)e * DDIM + dB + w * 32 + srow) * FDIM + soct * 8;
  const short* bS1 = bS0 + 16 * FDIM;

  int fragA = wr * 8 * 512 + blk * 8;
  int fragB = 8192 + wc * 4 * 512 + blk * 8;
  int dstA = w * 1024;
  int dstB = 8192 + w * 1024;

  f32x4 acc[8][4];
#pragma unroll
  for (int m = 0; m < 8; m++)
#pragma unroll
    for (int n = 0; n < 4; n++) acc[m][n] = (f32x4){0.f, 0.f, 0.f, 0.f};

#define STAGE_A2(u_) { int s_ = ((u_) & 3) * 16384; int k_ = (u_) * 32; \
    gl16(aS0 + k_, lds + s_ + dstA); gl16(aS1 + k_, lds + s_ + dstA + 512); }
#define STAGE_B2(u_) { int s_ = ((u_) & 3) * 16384; int k_ = (u_) * 32; \
    gl16(bS0 + k_, lds + s_ + dstB); gl16(bS1 + k_, lds + s_ + dstB + 512); }

  STAGE_A2(0); STAGE_B2(0); STAGE_A2(1); STAGE_B2(1);
  asm volatile("s_waitcnt vmcnt(4)" ::: "memory");
  __builtin_amdgcn_s_barrier();

  const int NT = FDIM / 32;   // 64
  for (int u = 0; u < NT; ++u) {
    int s = (u & 3) * 16384;
    bf16x8 a0[4], b0[4];
#pragma unroll
    for (int m = 0; m < 4; m++) a0[m] = *(const bf16x8*)(lds + s + fragA + m * 512);
#pragma unroll
    for (int n = 0; n < 4; n++) b0[n] = *(const bf16x8*)(lds + s + fragB + n * 512);
    if (u + 2 < NT) STAGE_A2(u + 2);
    __builtin_amdgcn_s_barrier();
    __builtin_amdgcn_s_setprio(1);
#pragma unroll
    for (int m = 0; m < 4; m++)
#pragma unroll
      for (int n = 0; n < 4; n++)
        acc[m][n] = __builtin_amdgcn_mfma_f32_16x16x32_bf16(a0[m], b0[n], acc[m][n], 0, 0, 0);
    __builtin_amdgcn_s_setprio(0);
    bf16x8 a1[4];
#pragma unroll
    for (int m = 0; m < 4; m++) a1[m] = *(const bf16x8*)(lds + s + fragA + (4 + m) * 512);
    if (u + 2 < NT) { STAGE_B2(u + 2); asm volatile("s_waitcnt vmcnt(4)" ::: "memory"); }
    else            { asm volatile("s_waitcnt vmcnt(0)" ::: "memory"); }
    __builtin_amdgcn_s_barrier();
    __builtin_amdgcn_s_setprio(1);
#pragma unroll
    for (int m = 0; m < 4; m++)
#pragma unroll
      for (int n = 0; n < 4; n++)
        acc[4 + m][n] = __builtin_amdgcn_mfma_f32_16x16x32_bf16(a1[m], b0[n], acc[4 + m][n], 0, 0, 0);
    __builtin_amdgcn_s_setprio(0);
  }

#pragma unroll
  for (int m = 0; m < 8; m++) {
#pragma unroll
    for (int j = 0; j < 4; j++) {
      int grow = rowBase + wr * 128 + m * 16 + gg * 4 + j;
      if (grow < segEnd) {
        short* op = outs + (size_t)grow * DDIM + dB + wc * 64 + r15;
#pragma unroll
        for (int n = 0; n < 4; n++)
          op[n * 16] = (short)f2bf(acc[m][n][j]);
      }
    }
  }
#undef STAGE_A2
#undef STAGE_B2
}

// ------------- combine: y[tok] = w0*outs[row0] + w1*outs[row1] -------------
__global__ void combine(const short* __restrict__ outs, const int* __restrict__ tk_row,
                        const float* __restrict__ tk_w, float* __restrict__ y) {
  int n = blockIdx.x;
  int t = threadIdx.x;
  int r0 = tk_row[2 * n], r1 = tk_row[2 * n + 1];
  float w0 = tk_w[2 * n], w1 = tk_w[2 * n + 1];
  bf16x4 a = *(const bf16x4*)(outs + (size_t)r0 * DDIM + t * 4);
  bf16x4 b = *(const bf16x4*)(outs + (size_t)r1 * DDIM + t * 4);
  float4 o;
  o.x = w0 * bf2f(a[0]) + w1 * bf2f(b[0]);
  o.y = w0 * bf2f(a[1]) + w1 * bf2f(b[1]);
  o.z = w0 * bf2f(a[2]) + w1 * bf2f(b[2]);
  o.w = w0 * bf2f(a[3]) + w1 * bf2f(b[3]);
  *(float4*)(y + (size_t)n * DDIM + t * 4) = o;
}

extern "C" void kernel_launch(void* const* d_in, const int* in_sizes, int n_in,
                              void* d_out, int out_size, void* d_ws, size_t ws_size,
                              hipStream_t stream) {
  const float* x      = (const float*)d_in[0];
  const float* gw     = (const float*)d_in[1];
  const float* w_gate = (const float*)d_in[2];
  const float* w_up   = (const float*)d_in[3];
  const float* w_down = (const float*)d_in[4];
  float* y = (float*)d_out;
  (void)in_sizes; (void)n_in; (void)ws_size; (void)out_size;

  char* ws = (char*)d_ws;
  size_t off = 0;
  auto alloc = [&](size_t bytes) -> void* {
    void* p = ws + off; off += (bytes + 255) & ~(size_t)255; return p;
  };
  short* wb1g      = (short*)alloc((size_t)NEXP * FDIM * DDIM * 2);   // [E][F][D] bf16
  short* wb1u      = (short*)alloc((size_t)NEXP * FDIM * DDIM * 2);   // [E][F][D] bf16
  short* wb2       = (short*)alloc((size_t)NEXP * DDIM * FDIM * 2);   // [E][D][F] bf16
  short* xg        = (short*)alloc((size_t)(NKROW + 256) * DDIM * 2); // gathered rows; REUSED as outs
  short* hbuf      = (short*)alloc((size_t)(NKROW + 256) * FDIM * 2); // SwiGLU output
  int*   tk_e      = (int*)alloc((size_t)NKROW * 4);
  float* tk_w      = (float*)alloc((size_t)NKROW * 4);
  int*   tk_row    = (int*)alloc((size_t)NKROW * 4);
  int*   tileE     = (int*)alloc(MAXT * 4);
  int*   tileRow   = (int*)alloc(MAXT * 4);
  int*   nTiles    = (int*)alloc(256);
  int*   offsets   = (int*)alloc(256);
  short* outs      = xg;   // xg is dead after gemm1; same size [NKROW+256][DDIM]

  transpose_cvt<<<dim3(FDIM / 64, DDIM / 64, NEXP), 256, 0, stream>>>(w_gate, wb1g, DDIM, FDIM);
  transpose_cvt<<<dim3(FDIM / 64, DDIM / 64, NEXP), 256, 0, stream>>>(w_up,   wb1u, DDIM, FDIM);
  transpose_cvt<<<dim3(DDIM / 64, FDIM / 64, NEXP), 256, 0, stream>>>(w_down, wb2,  FDIM, DDIM);
  gate_kernel<<<NTOK / 4, 256, 0, stream>>>(x, gw, tk_e, tk_w);
  build_index<<<1, 256, 0, stream>>>(tk_e, tk_row, offsets, tileE, tileRow, nTiles);
  build_rows<<<NKROW, 256, 0, stream>>>(x, tk_row, xg);
  gemm1<<<dim3(FDIM / 128, MAXT), 512, 0, stream>>>(xg, wb1g, wb1u, tileE, tileRow, nTiles, offsets, hbuf);
  gemm2<<<dim3(DDIM / 256, MAXT), 512, 0, stream>>>(hbuf, wb2, tileE, tileRow, nTiles, offsets, outs);
  combine<<<NTOK, 256, 0, stream>>>(outs, tk_row, tk_w, y);
}